// Round 1
// baseline (2647.658 us; speedup 1.0000x reference)
//
#include <hip/hip_runtime.h>
#include <hip/hip_bf16.h>

#define DEPTH_T 11
#define HDIM 1024
#define VDIM 32001
#define NNODES 4095   // 2^12 - 1

typedef __attribute__((ext_vector_type(8))) short bf16x8;
typedef __attribute__((ext_vector_type(4))) float floatx4;

// Pre-order position of BFS/heap node m (0-based) in a perfect binary tree of
// depth DEPTH_T. Path bits of (m+1) below the leading 1, MSB-first: descending
// right at level i skips the left subtree of size 2^(DEPTH_T-i+1)-1.
__device__ __forceinline__ int preorder_pos(int m) {
    int q = m + 1;
    int d = 31 - __clz(q);
    int pos = 0;
    for (int i = 1; i <= d; ++i) {
        int b = (q >> (d - i)) & 1;
        pos += 1 + b * ((1 << (DEPTH_T - i + 1)) - 1);
    }
    return pos;
}

#define BM 128
#define BN 128
#define BK 32

// C = A [M,K] @ B (given as Bt [N,K], both bf16 row-major) + bias[N]
// MODE 0: out bf16 [M,N] = sigmoid(acc + bias)
// MODE 1: out bf16 [M,N] = acc + bias
// MODE 2: out f32  [*,N] = acc + bias, rows scattered by preorder_pos
template<int MODE>
__global__ __launch_bounds__(256, 2) void gemm_bt(
    const __hip_bfloat16* __restrict__ A,
    const __hip_bfloat16* __restrict__ Bt,
    const float* __restrict__ bias,
    void* __restrict__ outp,
    int M, int N, int K)
{
    __shared__ __align__(16) __hip_bfloat16 As[BM][BK];
    __shared__ __align__(16) __hip_bfloat16 Bs[BN][BK];

    const int tid  = threadIdx.x;
    const int wave = tid >> 6;
    const int lane = tid & 63;
    const int m0 = blockIdx.y * BM;
    const int n0 = blockIdx.x * BN;
    const int wm = (wave & 1) * 64;
    const int wn = (wave >> 1) * 64;

    floatx4 acc[4][4];
#pragma unroll
    for (int i = 0; i < 4; ++i)
#pragma unroll
        for (int j = 0; j < 4; ++j) acc[i][j] = (floatx4)0.0f;

    const int lrow = lane >> 2;        // 0..15 : row within 16-row staging slab
    const int lcol = (lane & 3) * 8;   // 0,8,16,24 : element col within BK
    const int fr = lane & 15;          // fragment row index
    const int fk = (lane >> 4) * 8;    // fragment k offset

    for (int k0 = 0; k0 < K; k0 += BK) {
        __syncthreads();
        // Stage A tile: each wave issues 2 global_load_lds (16 rows x 64B each).
        // LDS dst is wave-uniform base; HW scatters lane*16B (guide §5).
#pragma unroll
        for (int t = 0; t < 2; ++t) {
            const int r = (wave * 2 + t) * 16;
            int gm = m0 + r + lrow; gm = gm < M ? gm : M - 1;   // clamp OOB rows
            const __hip_bfloat16* gp = A + (size_t)gm * K + (k0 + lcol);
            __builtin_amdgcn_global_load_lds(
                (const __attribute__((address_space(1))) void*)gp,
                (__attribute__((address_space(3))) void*)(&As[r][0]),
                16, 0, 0);
        }
#pragma unroll
        for (int t = 0; t < 2; ++t) {
            const int r = (wave * 2 + t) * 16;
            int gn = n0 + r + lrow; gn = gn < N ? gn : N - 1;
            const __hip_bfloat16* gp = Bt + (size_t)gn * K + (k0 + lcol);
            __builtin_amdgcn_global_load_lds(
                (const __attribute__((address_space(1))) void*)gp,
                (__attribute__((address_space(3))) void*)(&Bs[r][0]),
                16, 0, 0);
        }
        __syncthreads();

        bf16x8 af[4], bfv[4];
#pragma unroll
        for (int i = 0; i < 4; ++i)
            af[i] = *(const bf16x8*)(&As[wm + i * 16 + fr][fk]);
#pragma unroll
        for (int j = 0; j < 4; ++j)
            bfv[j] = *(const bf16x8*)(&Bs[wn + j * 16 + fr][fk]);
#pragma unroll
        for (int i = 0; i < 4; ++i)
#pragma unroll
            for (int j = 0; j < 4; ++j)
                acc[i][j] = __builtin_amdgcn_mfma_f32_16x16x32_bf16(
                    af[i], bfv[j], acc[i][j], 0, 0, 0);
    }

    // C/D layout: col = lane&15, row = (lane>>4)*4 + reg  (guide §3, m89/m91)
    const int rq = (lane >> 4) * 4;
    if (MODE == 2) {
        float* O = (float*)outp;
#pragma unroll
        for (int i = 0; i < 4; ++i) {
#pragma unroll
            for (int r = 0; r < 4; ++r) {
                const int gm = m0 + wm + i * 16 + rq + r;
                if (gm >= M) continue;
                const size_t orow = (size_t)preorder_pos(gm) * N;
#pragma unroll
                for (int j = 0; j < 4; ++j) {
                    const int gn = n0 + wn + j * 16 + fr;
                    if (gn < N) O[orow + gn] = acc[i][j][r] + bias[gn];
                }
            }
        }
    } else {
        __hip_bfloat16* O = (__hip_bfloat16*)outp;
#pragma unroll
        for (int i = 0; i < 4; ++i) {
#pragma unroll
            for (int r = 0; r < 4; ++r) {
                const int gm = m0 + wm + i * 16 + rq + r;
                if (gm >= M) continue;
#pragma unroll
                for (int j = 0; j < 4; ++j) {
                    const int gn = n0 + wn + j * 16 + fr;
                    if (gn < N) {
                        float v = acc[i][j][r] + bias[gn];
                        if (MODE == 0) v = 1.0f / (1.0f + __expf(-v));
                        O[(size_t)gm * N + gn] = __float2bfloat16(v);
                    }
                }
            }
        }
    }
}

// in [R,C] f32 row-major  ->  outT [C,R] bf16 row-major
__global__ __launch_bounds__(256) void transpose_to_bf16(
    const float* __restrict__ in, __hip_bfloat16* __restrict__ outT, int R, int C)
{
    __shared__ float tile[32][33];
    const int c0 = blockIdx.x * 32, r0 = blockIdx.y * 32;
    const int tx = threadIdx.x & 31, ty = threadIdx.x >> 5;   // ty: 0..7
#pragma unroll
    for (int i = 0; i < 32; i += 8) {
        int r = r0 + ty + i, c = c0 + tx;
        tile[ty + i][tx] = (r < R && c < C) ? in[(size_t)r * C + c] : 0.0f;
    }
    __syncthreads();
#pragma unroll
    for (int i = 0; i < 32; i += 8) {
        int rr = c0 + ty + i;   // out row = original col
        int cc = r0 + tx;       // out col = original row
        if (rr < C && cc < R) outT[(size_t)rr * R + cc] = __float2bfloat16(tile[tx][ty + i]);
    }
}

__global__ __launch_bounds__(256) void convert_root(
    const float* __restrict__ in, __hip_bfloat16* __restrict__ out)
{
    int i = blockIdx.x * 256 + threadIdx.x;
    if (i < HDIM) out[i] = __float2bfloat16(in[i]);
}

// In-place log_softmax per row; one block per row, online max/sum.
__global__ __launch_bounds__(256) void logsoftmax_rows(float* __restrict__ O, int n)
{
    __shared__ float sm[256], ssum[256];
    const int tid = threadIdx.x;
    float* p = O + (size_t)blockIdx.x * n;
    float m = -3.0e38f, s = 0.0f;
    for (int j = tid; j < n; j += 256) {
        float x = p[j];
        float nm = fmaxf(m, x);
        s = s * __expf(m - nm) + __expf(x - nm);
        m = nm;
    }
    sm[tid] = m; ssum[tid] = s;
    __syncthreads();
    for (int off = 128; off > 0; off >>= 1) {
        if (tid < off) {
            float m2 = sm[tid + off], s2 = ssum[tid + off];
            float nm = fmaxf(sm[tid], m2);
            ssum[tid] = ssum[tid] * __expf(sm[tid] - nm) + s2 * __expf(m2 - nm);
            sm[tid] = nm;
        }
        __syncthreads();
    }
    const float lse = sm[0] + __logf(ssum[0]);
    for (int j = tid; j < n; j += 256) p[j] -= lse;
}

extern "C" void kernel_launch(void* const* d_in, const int* in_sizes, int n_in,
                              void* d_out, int out_size, void* d_ws, size_t ws_size,
                              hipStream_t stream)
{
    const float* root = (const float*)d_in[0];
    const float* W1v  = (const float*)d_in[1];   // [1024, 2048]
    const float* b1v  = (const float*)d_in[2];   // [2048]
    const float* W2v  = (const float*)d_in[3];   // [2048, 32001]
    const float* b2v  = (const float*)d_in[4];   // [32001]
    const float* W1c  = (const float*)d_in[5];   // [1024, 2048]
    const float* b1c  = (const float*)d_in[6];   // [2048]
    const float* W2c  = (const float*)d_in[7];   // [2048, 2048]
    const float* b2c  = (const float*)d_in[8];   // [2048]

    // ws layout (bytes), total ~169 MB:
    char* ws = (char*)d_ws;
    __hip_bfloat16* Hall = (__hip_bfloat16*)(ws + 0);            // 4095x1024 bf16 (8.0 MB region)
    __hip_bfloat16* X1   = (__hip_bfloat16*)(ws +  8388608ull);  // 4095x2048 bf16 (16 MB region)
    __hip_bfloat16* Tt   = (__hip_bfloat16*)(ws + 25165824ull);  // 1024x2048 bf16 (4 MB)
    __hip_bfloat16* W1vT = (__hip_bfloat16*)(ws + 29360128ull);  // 2048x1024 (4 MB)
    __hip_bfloat16* W1cT = (__hip_bfloat16*)(ws + 33554432ull);  // 2048x1024 (4 MB)
    __hip_bfloat16* W2cT = (__hip_bfloat16*)(ws + 37748736ull);  // 2048x2048 (8 MB)
    __hip_bfloat16* W2vT = (__hip_bfloat16*)(ws + 46137344ull);  // 32001x2048 (125 MB)

    dim3 blk(256);

    // Weight conversions (B^T bf16 layouts) — must rerun every call (ws re-poisoned).
    transpose_to_bf16<<<dim3(64,   32), blk, 0, stream>>>(W1v, W1vT, 1024, 2048);
    transpose_to_bf16<<<dim3(1001, 64), blk, 0, stream>>>(W2v, W2vT, 2048, VDIM);
    transpose_to_bf16<<<dim3(64,   32), blk, 0, stream>>>(W1c, W1cT, 1024, 2048);
    transpose_to_bf16<<<dim3(64,   64), blk, 0, stream>>>(W2c, W2cT, 2048, 2048);
    convert_root<<<dim3(4), blk, 0, stream>>>(root, Hall);

    // Child phase: level d -> level d+1.  [2^d,2048] child output IS the
    // [2^(d+1),1024] hidden block in row-major memory (reshape is linear).
    for (int d = 0; d < DEPTH_T; ++d) {
        const int Md = 1 << d;
        __hip_bfloat16* Hd = Hall + (size_t)(Md - 1) * HDIM;
        __hip_bfloat16* Hn = Hall + (size_t)((2 << d) - 1) * HDIM;
        dim3 g1(16, (Md + BM - 1) / BM);
        gemm_bt<0><<<g1, blk, 0, stream>>>(Hd, W1cT, b1c, Tt, Md, 2048, 1024);
        gemm_bt<1><<<g1, blk, 0, stream>>>(Tt, W2cT, b2c, Hn, Md, 2048, 2048);
    }

    // Value phase, all nodes batched.
    gemm_bt<0><<<dim3(16, 32), blk, 0, stream>>>(Hall, W1vT, b1v, X1, NNODES, 2048, 1024);
    gemm_bt<2><<<dim3(251, 32), blk, 0, stream>>>(X1, W2vT, b2v, d_out, NNODES, VDIM, 2048);

    // In-place log_softmax (rows already pre-order-scattered by the GEMM).
    logsoftmax_rows<<<dim3(NNODES), blk, 0, stream>>>((float*)d_out, VDIM);
}

// Round 2
// 2074.536 us; speedup vs baseline: 1.2763x; 1.2763x over previous
//
#include <hip/hip_runtime.h>
#include <hip/hip_bf16.h>

#define DEPTH_T 11
#define HDIM 1024
#define VDIM 32001
#define NNODES 4095   // 2^12 - 1
#define LDV 32008     // padded bf16 logit row stride (x2B = 64016, 16B-aligned)

typedef __attribute__((ext_vector_type(8))) short bf16x8;
typedef __attribute__((ext_vector_type(8))) unsigned short ushort8;
typedef __attribute__((ext_vector_type(4))) float floatx4;

// Pre-order position of BFS/heap node m (0-based), perfect binary tree depth DEPTH_T.
__device__ __forceinline__ int preorder_pos(int m) {
    int q = m + 1;
    int d = 31 - __clz(q);
    int pos = 0;
    for (int i = 1; i <= d; ++i) {
        int b = (q >> (d - i)) & 1;
        pos += 1 + b * ((1 << (DEPTH_T - i + 1)) - 1);
    }
    return pos;
}

__device__ __forceinline__ float bf2f(unsigned short u) {
    return __uint_as_float(((unsigned)u) << 16);
}

#define BM 128
#define BN 128
#define BK 32

// C = A [M,K] @ Bt^T (Bt is [N,K] bf16 row-major) + bias[N]
// MODE 0: bf16 out = sigmoid(acc+bias)        MODE 1: bf16 out = acc+bias
// MODE 2: f32 out, rows scattered by preorder  MODE 3: bf16 out, rows scattered
// SWAPG: blockIdx.x walks M-tiles (consecutive blocks share a B strip -> L2 reuse)
template<int MODE, bool SWAPG>
__global__ __launch_bounds__(256, 2) void gemm_bt(
    const __hip_bfloat16* __restrict__ A,
    const __hip_bfloat16* __restrict__ Bt,
    const float* __restrict__ bias,
    void* __restrict__ outp,
    int M, int N, int K, int ldout)
{
    __shared__ __align__(16) __hip_bfloat16 As[BM][BK];
    __shared__ __align__(16) __hip_bfloat16 Bs[BN][BK];

    const int tid  = threadIdx.x;
    const int wave = tid >> 6;
    const int lane = tid & 63;
    const int m0 = (SWAPG ? blockIdx.x : blockIdx.y) * BM;
    const int n0 = (SWAPG ? blockIdx.y : blockIdx.x) * BN;
    const int wm = (wave & 1) * 64;
    const int wn = (wave >> 1) * 64;

    floatx4 acc[4][4];
#pragma unroll
    for (int i = 0; i < 4; ++i)
#pragma unroll
        for (int j = 0; j < 4; ++j) acc[i][j] = (floatx4)0.0f;

    const int lrow = lane >> 2;        // 0..15 : row within 16-row staging slab
    const int lcol = (lane & 3) * 8;   // element col within BK
    const int fr = lane & 15;          // fragment row index
    const int fk = (lane >> 4) * 8;    // fragment k offset

    for (int k0 = 0; k0 < K; k0 += BK) {
        __syncthreads();
#pragma unroll
        for (int t = 0; t < 2; ++t) {
            const int r = (wave * 2 + t) * 16;
            int gm = m0 + r + lrow; gm = gm < M ? gm : M - 1;
            const __hip_bfloat16* gp = A + (size_t)gm * K + (k0 + lcol);
            __builtin_amdgcn_global_load_lds(
                (const __attribute__((address_space(1))) void*)gp,
                (__attribute__((address_space(3))) void*)(&As[r][0]),
                16, 0, 0);
        }
#pragma unroll
        for (int t = 0; t < 2; ++t) {
            const int r = (wave * 2 + t) * 16;
            int gn = n0 + r + lrow; gn = gn < N ? gn : N - 1;
            const __hip_bfloat16* gp = Bt + (size_t)gn * K + (k0 + lcol);
            __builtin_amdgcn_global_load_lds(
                (const __attribute__((address_space(1))) void*)gp,
                (__attribute__((address_space(3))) void*)(&Bs[r][0]),
                16, 0, 0);
        }
        __syncthreads();

        bf16x8 af[4], bfv[4];
#pragma unroll
        for (int i = 0; i < 4; ++i)
            af[i] = *(const bf16x8*)(&As[wm + i * 16 + fr][fk]);
#pragma unroll
        for (int j = 0; j < 4; ++j)
            bfv[j] = *(const bf16x8*)(&Bs[wn + j * 16 + fr][fk]);
#pragma unroll
        for (int i = 0; i < 4; ++i)
#pragma unroll
            for (int j = 0; j < 4; ++j)
                acc[i][j] = __builtin_amdgcn_mfma_f32_16x16x32_bf16(
                    af[i], bfv[j], acc[i][j], 0, 0, 0);
    }

    // C/D layout: col = lane&15, row = (lane>>4)*4 + reg
    const int rq = (lane >> 4) * 4;
    if (MODE >= 2) {
#pragma unroll
        for (int i = 0; i < 4; ++i) {
#pragma unroll
            for (int r = 0; r < 4; ++r) {
                const int gm = m0 + wm + i * 16 + rq + r;
                if (gm >= M) continue;
                const size_t orow = (size_t)preorder_pos(gm) * ldout;
#pragma unroll
                for (int j = 0; j < 4; ++j) {
                    const int gn = n0 + wn + j * 16 + fr;
                    if (gn < N) {
                        float v = acc[i][j][r] + bias[gn];
                        if (MODE == 2) ((float*)outp)[orow + gn] = v;
                        else ((__hip_bfloat16*)outp)[orow + gn] = __float2bfloat16(v);
                    }
                }
            }
        }
    } else {
        __hip_bfloat16* O = (__hip_bfloat16*)outp;
#pragma unroll
        for (int i = 0; i < 4; ++i) {
#pragma unroll
            for (int r = 0; r < 4; ++r) {
                const int gm = m0 + wm + i * 16 + rq + r;
                if (gm >= M) continue;
#pragma unroll
                for (int j = 0; j < 4; ++j) {
                    const int gn = n0 + wn + j * 16 + fr;
                    if (gn < N) {
                        float v = acc[i][j][r] + bias[gn];
                        if (MODE == 0) v = 1.0f / (1.0f + __expf(-v));
                        O[(size_t)gm * ldout + gn] = __float2bfloat16(v);
                    }
                }
            }
        }
    }
}

// Small-M GEMM: no LDS, no barriers — loads software-pipeline via vmcnt.
// Each wave computes a 16(M)x16(N) tile; grid (N/64, ceil(M/16)).
// MODE 0: sigmoid->bf16   MODE 1: bias->bf16
template<int MODE>
__global__ __launch_bounds__(256) void gemm_small(
    const __hip_bfloat16* __restrict__ A,
    const __hip_bfloat16* __restrict__ Bt,
    const float* __restrict__ bias,
    __hip_bfloat16* __restrict__ O,
    int M, int N, int K)
{
    const int wave = threadIdx.x >> 6, lane = threadIdx.x & 63;
    const int n0 = blockIdx.x * 64 + wave * 16;
    const int m0 = blockIdx.y * 16;
    const int fr = lane & 15, fk = (lane >> 4) * 8;

    int am = m0 + fr; am = am < M ? am : M - 1;
    const __hip_bfloat16* ap = A + (size_t)am * K + fk;
    const __hip_bfloat16* bp = Bt + (size_t)(n0 + fr) * K + fk;

    floatx4 acc = (floatx4)0.0f;
#pragma unroll 8
    for (int k0 = 0; k0 < K; k0 += 32) {
        bf16x8 av = *(const bf16x8*)(ap + k0);
        bf16x8 bv = *(const bf16x8*)(bp + k0);
        acc = __builtin_amdgcn_mfma_f32_16x16x32_bf16(av, bv, acc, 0, 0, 0);
    }

    const int rq = (lane >> 4) * 4;
    const int gn = n0 + fr;
    const float b = bias[gn];
#pragma unroll
    for (int r = 0; r < 4; ++r) {
        const int gm = m0 + rq + r;
        if (gm >= M) continue;
        float v = acc[r] + b;
        if (MODE == 0) v = 1.0f / (1.0f + __expf(-v));
        O[(size_t)gm * N + gn] = __float2bfloat16(v);
    }
}

// in [R,C] f32 row-major -> outT [C,R] bf16 row-major. 64x64 tiles.
__global__ __launch_bounds__(256) void transpose_to_bf16(
    const float* __restrict__ in, __hip_bfloat16* __restrict__ outT, int R, int C)
{
    __shared__ float tile[64][65];
    const int c0 = blockIdx.x * 64, r0 = blockIdx.y * 64;
    const int tx = threadIdx.x & 63, ty = threadIdx.x >> 6;   // ty: 0..3
#pragma unroll
    for (int i = 0; i < 64; i += 4) {
        int r = r0 + ty + i, c = c0 + tx;
        tile[ty + i][tx] = (r < R && c < C) ? in[(size_t)r * C + c] : 0.0f;
    }
    __syncthreads();
#pragma unroll
    for (int i = 0; i < 64; i += 4) {
        int rr = c0 + ty + i, cc = r0 + tx;
        if (rr < C && cc < R) outT[(size_t)rr * R + cc] = __float2bfloat16(tile[tx][ty + i]);
    }
}

__global__ __launch_bounds__(256) void convert_root(
    const float* __restrict__ in, __hip_bfloat16* __restrict__ out)
{
    int i = blockIdx.x * 256 + threadIdx.x;
    if (i < HDIM) out[i] = __float2bfloat16(in[i]);
}

// Log-softmax over bf16 logit rows (stride LDV), writing fp32 rows (stride VDIM).
// Row cached in LDS; 3 sweeps (max / sum-exp / subtract), wred in tail of smem.
__global__ __launch_bounds__(256) void logsoftmax_bf16(
    const unsigned short* __restrict__ L, float* __restrict__ O)
{
    extern __shared__ char smem[];
    unsigned short* rb = (unsigned short*)smem;     // 32001 entries (64016 B w/ pad)
    float* wred = (float*)(smem + 64016);           // 8 floats
    const int tid = threadIdx.x, lane = tid & 63, wv = tid >> 6;
    const unsigned short* src = L + (size_t)blockIdx.x * LDV;

    float m = -3.0e38f;
    for (int j = tid * 8; j < 32000; j += 2048) {
        ushort8 u = *(const ushort8*)(src + j);
        *(ushort8*)(rb + j) = u;
#pragma unroll
        for (int t = 0; t < 8; ++t) m = fmaxf(m, bf2f(u[t]));
    }
    if (tid == 0) { unsigned short u = src[32000]; rb[32000] = u; m = fmaxf(m, bf2f(u)); }
#pragma unroll
    for (int off = 32; off; off >>= 1) m = fmaxf(m, __shfl_xor(m, off, 64));
    if (lane == 0) wred[wv] = m;
    __syncthreads();
    const float M4 = fmaxf(fmaxf(wred[0], wred[1]), fmaxf(wred[2], wred[3]));

    float s = 0.0f;
    for (int j = tid * 8; j < 32000; j += 2048) {
        ushort8 u = *(const ushort8*)(rb + j);
#pragma unroll
        for (int t = 0; t < 8; ++t) s += __expf(bf2f(u[t]) - M4);
    }
    if (tid == 0) s += __expf(bf2f(rb[32000]) - M4);
#pragma unroll
    for (int off = 32; off; off >>= 1) s += __shfl_xor(s, off, 64);
    if (lane == 0) wred[4 + wv] = s;
    __syncthreads();
    const float lse = M4 + __logf(wred[4] + wred[5] + wred[6] + wred[7]);

    float* dst = O + (size_t)blockIdx.x * VDIM;
    for (int j = tid * 8; j < 32000; j += 2048) {
        ushort8 u = *(const ushort8*)(rb + j);
#pragma unroll
        for (int t = 0; t < 8; ++t) dst[j + t] = bf2f(u[t]) - lse;
    }
    if (tid == 0) dst[32000] = bf2f(rb[32000]) - lse;
}

// Fallback: in-place fp32 log_softmax (used only if ws too small for bf16 logits).
__global__ __launch_bounds__(256) void logsoftmax_rows(float* __restrict__ O, int n)
{
    __shared__ float sm[256], ssum[256];
    const int tid = threadIdx.x;
    float* p = O + (size_t)blockIdx.x * n;
    float m = -3.0e38f, s = 0.0f;
    for (int j = tid; j < n; j += 256) {
        float x = p[j];
        float nm = fmaxf(m, x);
        s = s * __expf(m - nm) + __expf(x - nm);
        m = nm;
    }
    sm[tid] = m; ssum[tid] = s;
    __syncthreads();
    for (int off = 128; off > 0; off >>= 1) {
        if (tid < off) {
            float m2 = sm[tid + off], s2 = ssum[tid + off];
            float nm = fmaxf(sm[tid], m2);
            ssum[tid] = ssum[tid] * __expf(sm[tid] - nm) + s2 * __expf(m2 - nm);
            sm[tid] = nm;
        }
        __syncthreads();
    }
    const float lse = sm[0] + __logf(ssum[0]);
    for (int j = tid; j < n; j += 256) p[j] -= lse;
}

extern "C" void kernel_launch(void* const* d_in, const int* in_sizes, int n_in,
                              void* d_out, int out_size, void* d_ws, size_t ws_size,
                              hipStream_t stream)
{
    const float* root = (const float*)d_in[0];
    const float* W1v  = (const float*)d_in[1];   // [1024, 2048]
    const float* b1v  = (const float*)d_in[2];
    const float* W2v  = (const float*)d_in[3];   // [2048, 32001]
    const float* b2v  = (const float*)d_in[4];
    const float* W1c  = (const float*)d_in[5];   // [1024, 2048]
    const float* b1c  = (const float*)d_in[6];
    const float* W2c  = (const float*)d_in[7];   // [2048, 2048]
    const float* b2c  = (const float*)d_in[8];

    char* ws = (char*)d_ws;
    __hip_bfloat16* Hall = (__hip_bfloat16*)(ws + 0);             // 4095x1024 (8 MB rgn)
    __hip_bfloat16* X1   = (__hip_bfloat16*)(ws +   8388608ull);  // 4095x2048 (16 MB rgn)
    __hip_bfloat16* Tt   = (__hip_bfloat16*)(ws +  25165824ull);  // 1024x2048 (4 MB)
    __hip_bfloat16* W1vT = (__hip_bfloat16*)(ws +  29360128ull);  // 2048x1024 (4 MB)
    __hip_bfloat16* W1cT = (__hip_bfloat16*)(ws +  33554432ull);  // 2048x1024 (4 MB)
    __hip_bfloat16* W2cT = (__hip_bfloat16*)(ws +  37748736ull);  // 2048x2048 (8 MB)
    __hip_bfloat16* W2vT = (__hip_bfloat16*)(ws +  46137344ull);  // 32001x2048 (ends 177,213,440)
    __hip_bfloat16* Lb   = (__hip_bfloat16*)(ws + 177213440ull);  // 4095xLDV bf16 logits
    const bool bf16_logits = ws_size >= 177213440ull + (size_t)NNODES * LDV * 2;

    dim3 blk(256);

    transpose_to_bf16<<<dim3( 32, 16), blk, 0, stream>>>(W1v, W1vT, 1024, 2048);
    transpose_to_bf16<<<dim3(501, 32), blk, 0, stream>>>(W2v, W2vT, 2048, VDIM);
    transpose_to_bf16<<<dim3( 32, 16), blk, 0, stream>>>(W1c, W1cT, 1024, 2048);
    transpose_to_bf16<<<dim3( 32, 32), blk, 0, stream>>>(W2c, W2cT, 2048, 2048);
    convert_root<<<dim3(4), blk, 0, stream>>>(root, Hall);

    // Child phase: level d -> d+1. Child output [2^d,2048] IS hidden block
    // [2^(d+1),1024] in row-major memory.
    for (int d = 0; d < DEPTH_T; ++d) {
        const int Md = 1 << d;
        __hip_bfloat16* Hd = Hall + (size_t)(Md - 1) * HDIM;
        __hip_bfloat16* Hn = Hall + (size_t)((2 << d) - 1) * HDIM;
        if (Md <= 256) {   // latency-bound regime: LDS-free pipelined kernel
            dim3 g(32, (Md + 15) / 16);
            gemm_small<0><<<g, blk, 0, stream>>>(Hd, W1cT, b1c, Tt, Md, 2048, 1024);
            gemm_small<1><<<g, blk, 0, stream>>>(Tt, W2cT, b2c, Hn, Md, 2048, 2048);
        } else {
            dim3 g(16, Md / 128);
            gemm_bt<0, false><<<g, blk, 0, stream>>>(Hd, W1cT, b1c, Tt, Md, 2048, 1024, 2048);
            gemm_bt<1, false><<<g, blk, 0, stream>>>(Tt, W2cT, b2c, Hn, Md, 2048, 2048, 2048);
        }
    }

    // Value phase.
    gemm_bt<0, false><<<dim3(16, 32), blk, 0, stream>>>(Hall, W1vT, b1v, X1, NNODES, 2048, 1024, 2048);
    if (bf16_logits) {
        gemm_bt<3, true><<<dim3(32, 251), blk, 0, stream>>>(X1, W2vT, b2v, Lb, NNODES, VDIM, 2048, LDV);
        logsoftmax_bf16<<<dim3(NNODES), blk, 64048, stream>>>((const unsigned short*)Lb, (float*)d_out);
    } else {
        gemm_bt<2, true><<<dim3(32, 251), blk, 0, stream>>>(X1, W2vT, b2v, d_out, NNODES, VDIM, 2048, VDIM);
        logsoftmax_rows<<<dim3(NNODES), blk, 0, stream>>>((float*)d_out, VDIM);
    }
}